// Round 9
// baseline (1667.062 us; speedup 1.0000x reference)
//
#include <hip/hip_runtime.h>
#include <hip/hip_bf16.h>

#define H_ 2048
#define E_ 64
#define I_ 768
#define K_ 8
#define GT 6          // gateup token tiles per pass (96 tokens)
#define GTD 5         // down token tiles per pass (80 tokens)

typedef __attribute__((ext_vector_type(8))) __bf16 bf16x8;
typedef __attribute__((ext_vector_type(4))) float f32x4;

__device__ inline unsigned short f2bfbits(float f) {
  unsigned u = __float_as_uint(f);
  u = (u + 0x7fffu + ((u >> 16) & 1u)) >> 16;   // RNE
  return (unsigned short)u;
}
__device__ inline f32x4 mfma16(bf16x8 a, bf16x8 b, f32x4 c) {
  return __builtin_amdgcn_mfma_f32_16x16x32_bf16(a, b, c, 0, 0, 0);
}
__device__ inline bf16x8 packv(f32x4 a, f32x4 b) {
  union { unsigned u[4]; bf16x8 v; } r;
  asm("v_cvt_pk_bf16_f32 %0, %1, %2" : "=v"(r.u[0]) : "v"(a[0]), "v"(a[1]));
  asm("v_cvt_pk_bf16_f32 %0, %1, %2" : "=v"(r.u[1]) : "v"(a[2]), "v"(a[3]));
  asm("v_cvt_pk_bf16_f32 %0, %1, %2" : "=v"(r.u[2]) : "v"(b[0]), "v"(b[1]));
  asm("v_cvt_pk_bf16_f32 %0, %1, %2" : "=v"(r.u[3]) : "v"(b[2]), "v"(b[3]));
  return r.v;
}
__device__ inline void dma16(const float* g, float* l) {
  __builtin_amdgcn_global_load_lds(
      (const __attribute__((address_space(1))) float*)g,
      (__attribute__((address_space(3))) float*)l, 16, 0, 0);
}
template <int OFS>
__device__ inline f32x4 dsr(unsigned addr) {
  f32x4 d;
  asm volatile("ds_read_b128 %0, %1 offset:%2" : "=v"(d) : "v"(addr), "n"(OFS));
  return d;
}
#define SB() __builtin_amdgcn_sched_barrier(0)
#define LGKM0() do { asm volatile("s_waitcnt lgkmcnt(0)" ::: "memory"); SB(); } while (0)

// ================= READ-CEILING PROBES (diagnostic, this round only) ========
// probe_a: best-case plain float4 grid-stride streaming read.
__global__ __launch_bounds__(256) void probe_a(
    const float4* __restrict__ p, float* __restrict__ sink, long n4, int passes) {
  long stride = (long)gridDim.x * 256;
  float acc = 0.f;
  for (int ps = 0; ps < passes; ++ps) {
    for (long i = (long)blockIdx.x * 256 + threadIdx.x; i < n4; i += stride) {
      float4 v = p[i];
      acc += v.x + v.y + v.z + v.w;
    }
  }
  asm volatile("" :: "v"(acc));
  if (acc == 1.2345e30f) *sink = acc;   // never taken; keeps loads live
}

// probe_c: global_load_lds streaming read, 1KB/instruction, vmcnt(15)-paced.
__global__ __launch_bounds__(256, 2) void probe_c(
    const float* __restrict__ p, float* __restrict__ sink, long nf, int passes) {
  __shared__ __align__(16) float buf[4][4096];   // 16KB per wave
  int wv = threadIdx.x >> 6, lane = threadIdx.x & 63;
  long waves = (long)gridDim.x * 4;
  long gwid = (long)blockIdx.x * 4 + wv;
  long perWave = nf / waves;                      // multiple of 256
  const float* base = p + gwid * perWave + lane * 4;
  long iters = perWave / 256;
  for (int ps = 0; ps < passes; ++ps) {
    for (long it = 0; it < iters; ++it) {
      dma16(base + it * 256, &buf[wv][(int)(it & 15) * 256]);
      asm volatile("s_waitcnt vmcnt(15)" ::: "memory");
    }
  }
  asm volatile("s_waitcnt vmcnt(0)" ::: "memory");
  __syncthreads();
  float v = buf[wv][lane];
  if (v == 1.2345e30f) *sink = v;
}

// ---------------- Router (fp32-exact) + fused x->bf16 cast + cnt zero --------
__global__ __launch_bounds__(256) void router_kernel(
    const float* __restrict__ x, const float* __restrict__ gw,
    int* __restrict__ topk_id, float* __restrict__ topk_w,
    __hip_bfloat16* __restrict__ xb, int* __restrict__ cnt) {
  __shared__ float xs[H_];
  __shared__ float probs[E_];
  int m = blockIdx.x;
  if (m == 0 && threadIdx.x < E_) cnt[threadIdx.x] = 0;
  const float* xr = x + (size_t)m * H_;
  for (int i = threadIdx.x; i < H_; i += 256) xs[i] = xr[i];
  __syncthreads();
  unsigned short* xbr = reinterpret_cast<unsigned short*>(xb) + (size_t)m * H_;
  for (int i = threadIdx.x; i < H_; i += 256) xbr[i] = f2bfbits(xs[i]);
  int e = threadIdx.x >> 2, part = threadIdx.x & 3;
  const float* gr = gw + (size_t)e * H_ + part * (H_ / 4);
  const float* xx = xs + part * (H_ / 4);
  float s = 0.f;
#pragma unroll 8
  for (int i = 0; i < H_ / 4; ++i) s = fmaf(xx[i], gr[i], s);
  s += __shfl_xor(s, 1);
  s += __shfl_xor(s, 2);
  if (part == 0) probs[e] = s;
  __syncthreads();
  if (threadIdx.x == 0) {
    float mx = -1e30f;
    for (int i = 0; i < E_; ++i) mx = fmaxf(mx, probs[i]);
    float sum = 0.f;
    for (int i = 0; i < E_; ++i) { float p = expf(probs[i] - mx); probs[i] = p; sum += p; }
    float inv = 1.f / sum;
    for (int i = 0; i < E_; ++i) probs[i] *= inv;
    float bw[K_]; int bi[K_]; float wsum = 0.f;
#pragma unroll
    for (int k = 0; k < K_; ++k) {
      float best = -1.f; int b = 0;
      for (int i = 0; i < E_; ++i) if (probs[i] > best) { best = probs[i]; b = i; }
      bw[k] = best; bi[k] = b; wsum += best; probs[b] = -2.f;
    }
    float winv = 1.f / wsum;
#pragma unroll
    for (int k = 0; k < K_; ++k) {
      topk_id[m * K_ + k] = bi[k];
      topk_w[m * K_ + k] = bw[k] * winv;
    }
  }
}

// ---------------- Expert list build ----------------
__global__ void scatter_kernel(const int* __restrict__ topk_id, int* cnt,
                               int* perEx, int MK, int M) {
  int idx = blockIdx.x * 256 + threadIdx.x;
  if (idx >= MK) return;
  int e = topk_id[idx];
  int pos = atomicAdd(cnt + e, 1);
  perEx[e * M + pos] = idx;  // idx == m*K_+k
}

__global__ void scan_kernel(const int* cnt, int* off) {
  if (threadIdx.x == 0) {
    int a = 0;
    for (int e = 0; e < E_; ++e) { off[e] = a; a += cnt[e]; }
    off[E_] = a;
  }
}

__global__ void compact_kernel(const int* __restrict__ cnt, const int* __restrict__ off,
                               const int* __restrict__ perEx,
                               int* __restrict__ entry_mk, int* __restrict__ slot2g, int M) {
  int e = blockIdx.x; int n = cnt[e]; int b = off[e];
  for (int p = threadIdx.x; p < n; p += 256) {
    int mk = perEx[e * M + p];
    entry_mk[b + p] = mk;
    slot2g[mk] = b + p;
  }
}

// ---------------- Gate/Up MFMA GEMM + SiLU -> ACT (bf16) ----------------
__global__ __launch_bounds__(256, 1) void gateup_mfma(
    const __hip_bfloat16* __restrict__ xb, const float* __restrict__ w13,
    const int* __restrict__ cnt, const int* __restrict__ off,
    const int* __restrict__ entry_mk, __hip_bfloat16* __restrict__ ACT) {
  __shared__ __align__(16) float lds[2][16384];   // 2 x 64KB
  const int NST = 16;                              // H/128
  int e = blockIdx.y;
  int ne = cnt[e];
  if (ne == 0) return;
  int base = off[e];
  int wv = threadIdx.x >> 6, lane = threadIdx.x & 63;
  int i0 = blockIdx.x * 64;
  int col = lane & 15, kq = lane >> 4;
  int half = lane >> 5, p = lane & 31;
  const float* w13e = w13 + (size_t)e * (2 * I_) * H_;
  int st0 = (blockIdx.x * 7 + blockIdx.y * 3) & (NST - 1);

  int rowC = (wv < 2) ? (i0 + 32 * wv + half) : (I_ + i0 + 32 * wv - 64 + half);
  const float* wbase = w13e + (size_t)rowC * H_;
  int xo[4];
#pragma unroll
  for (int j = 0; j < 4; ++j) xo[j] = (p ^ ((j << 1) | half)) * 4;

  auto issueD = [&](int s, int b) {
    int cs = s + st0; if (cs >= NST) cs -= NST;
    const float* bs = wbase + cs * 128;
#pragma unroll
    for (int q = 0; q < 16; ++q)
      dma16(bs + (size_t)(2 * q) * H_ + xo[q & 3], &lds[b][(16 * wv + q) * 256]);
  };

  unsigned laneOfs = (unsigned)((8 * wv + (col >> 1)) * 1024 + (col & 1) * 512 +
                                (((kq * 2) ^ (col & 7)) * 16));
  unsigned ldsBase = (unsigned)(size_t)(&lds[0][0]);
  int icol = i0 + 16 * wv + col;

  int ntile = (ne + 15) >> 4;
  for (int tb = 0; tb < ntile; tb += GT) {
    const __hip_bfloat16* arow0[GT];
#pragma unroll
    for (int t = 0; t < GT; ++t) {
      int pt = (tb + t) * 16 + col;
      int pc = pt < ne ? pt : ne - 1;
      int tok = entry_mk[base + pc] >> 3;
      arow0[t] = xb + (size_t)tok * H_ + kq * 8;
    }
    f32x4 accg[GT], accu[GT];
#pragma unroll
    for (int t = 0; t < GT; ++t) {
      accg[t] = (f32x4){0.f, 0.f, 0.f, 0.f};
      accu[t] = (f32x4){0.f, 0.f, 0.f, 0.f};
    }
    bf16x8 aS0[GT], aS1[GT], aS2[GT], aS3[GT];
    auto loadA = [&](bf16x8 (&dst)[GT], int kf) {
#pragma unroll
      for (int t = 0; t < GT; ++t)
        dst[t] = *reinterpret_cast<const bf16x8*>(arow0[t] + kf);
    };
    issueD(0, 0); SB();
    { int k0 = st0 * 128;
      loadA(aS0, k0); loadA(aS1, k0 + 32); loadA(aS2, k0 + 64); loadA(aS3, k0 + 96); }
    SB();
    issueD(1, 1); SB();

#define GJ(JOFS, AC)                                                     \
    {                                                                    \
      f32x4 g0 = dsr<(JOFS)>(a0), g1 = dsr<(JOFS)>(a1);                  \
      f32x4 u0 = dsr<(JOFS) + 32768>(a0), u1 = dsr<(JOFS) + 32768>(a1);  \
      LGKM0();                                                           \
      bf16x8 bg = packv(g0, g1), bu = packv(u0, u1);                     \
      _Pragma("unroll")                                                  \
      for (int t = 0; t < GT; ++t) {                                     \
        accg[t] = mfma16(AC[t], bg, accg[t]);                            \
        accu[t] = mfma16(AC[t], bu, accu[t]);                            \
      }                                                                  \
    }

    for (int s = 0; s < NST; ++s) {
      if (s < NST - 1) { asm volatile("s_waitcnt vmcnt(34)" ::: "memory"); }
      else             { asm volatile("s_waitcnt vmcnt(18)" ::: "memory"); }
      SB();
      __builtin_amdgcn_s_barrier();
      SB();
      unsigned a0 = ldsBase + (unsigned)((s & 1) * 65536) + laneOfs;
      unsigned a1 = a0 ^ 16u;
      GJ(0, aS0)
      GJ(128, aS1)
      GJ(256, aS2)
      GJ(384, aS3)
      if (s < NST - 1) {
        int cn = s + 1 + st0; if (cn >= NST) cn -= NST;
        int kn = cn * 128;
        loadA(aS0, kn); loadA(aS1, kn + 32); loadA(aS2, kn + 64); loadA(aS3, kn + 96);
      }
      SB();
      __builtin_amdgcn_s_barrier();
      SB();
      if (s + 2 < NST) { issueD(s + 2, s & 1); SB(); }
    }
#undef GJ

#pragma unroll
    for (int t = 0; t < GT; ++t) {
#pragma unroll
      for (int r = 0; r < 4; ++r) {
        int m = (tb + t) * 16 + kq * 4 + r;
        if (m < ne) {
          float gv = accg[t][r], uv = accu[t][r];
          float act = gv / (1.f + __expf(-gv)) * uv;
          reinterpret_cast<unsigned short*>(ACT)[(size_t)(base + m) * I_ + icol] =
              f2bfbits(act);
        }
      }
    }
  }
}

// ---------------- Down MFMA GEMM -> OUTS (fp32) ----------------
__global__ __launch_bounds__(256, 2) void down_mfma(
    const __hip_bfloat16* __restrict__ ACT, const float* __restrict__ w2,
    const int* __restrict__ cnt, const int* __restrict__ off,
    float* __restrict__ OUTS) {
  __shared__ __align__(16) float lds[2][8192];    // 2 x 32KB
  const int NST = 6;                               // I/128
  int e = blockIdx.y;
  int ne = cnt[e];
  if (ne == 0) return;
  int base = off[e];
  int wv = threadIdx.x >> 6, lane = threadIdx.x & 63;
  int h0 = blockIdx.x * 64;
  int col = lane & 15, kq = lane >> 4;
  int half = lane >> 5, p = lane & 31;
  const float* w2e = w2 + (size_t)e * H_ * I_;
  int st0 = (int)((unsigned)(blockIdx.x + blockIdx.y * 5) % (unsigned)NST);

  const float* wbase = w2e + (size_t)(h0 + 16 * wv + half) * I_;
  int xo[4];
#pragma unroll
  for (int j = 0; j < 4; ++j) xo[j] = (p ^ ((j << 1) | half)) * 4;

  auto issueD = [&](int s, int b) {
    int cs = s + st0; if (cs >= NST) cs -= NST;
    const float* bs = wbase + cs * 128;
#pragma unroll
    for (int q = 0; q < 8; ++q)
      dma16(bs + (size_t)(2 * q) * I_ + xo[q & 3], &lds[b][(8 * wv + q) * 256]);
  };

  unsigned laneOfs = (unsigned)((8 * wv + (col >> 1)) * 1024 + (col & 1) * 512 +
                                (((kq * 2) ^ (col & 7)) * 16));
  unsigned ldsBase = (unsigned)(size_t)(&lds[0][0]);
  int hcol = h0 + 16 * wv + col;

  int ntile = (ne + 15) >> 4;
  for (int tb = 0; tb < ntile; tb += GTD) {
    const __hip_bfloat16* arow0[GTD];
#pragma unroll
    for (int t = 0; t < GTD; ++t) {
      int pt = (tb + t) * 16 + col;
      int pc = pt < ne ? pt : ne - 1;
      arow0[t] = ACT + (size_t)(base + pc) * I_ + kq * 8;
    }
    f32x4 acc[GTD];
#pragma unroll
    for (int t = 0; t < GTD; ++t) acc[t] = (f32x4){0.f, 0.f, 0.f, 0.f};
    bf16x8 aS0[GTD], aS1[GTD], aS2[GTD], aS3[GTD];
    auto loadA = [&](bf16x8 (&dst)[GTD], int kf) {
#pragma unroll
      for (int t = 0; t < GTD; ++t)
        dst[t] = *reinterpret_cast<const bf16x8*>(arow0[t] + kf);
    };
    issueD(0, 0); SB();
    { int k0 = st0 * 128;
      loadA(aS0, k0); loadA(aS1, k0 + 32); loadA(aS2, k0 + 64); loadA(aS3, k0 + 96); }
    SB();
    issueD(1, 1); SB();

#define DJ(JOFS, AC)                                                     \
    {                                                                    \
      f32x4 w0 = dsr<(JOFS)>(a0), w1 = dsr<(JOFS)>(a1);                  \
      LGKM0();                                                           \
      bf16x8 bw = packv(w0, w1);                                         \
      _Pragma("unroll")                                                  \
      for (int t = 0; t < GTD; ++t) acc[t] = mfma16(AC[t], bw, acc[t]);  \
    }

    for (int s = 0; s < NST; ++s) {
      if (s < NST - 1) { asm volatile("s_waitcnt vmcnt(23)" ::: "memory"); }
      else             { asm volatile("s_waitcnt vmcnt(15)" ::: "memory"); }
      SB();
      __builtin_amdgcn_s_barrier();
      SB();
      unsigned a0 = ldsBase + (unsigned)((s & 1) * 32768) + laneOfs;
      unsigned a1 = a0 ^ 16u;
      DJ(0, aS0)
      DJ(128, aS1)
      DJ(256, aS2)
      DJ(384, aS3)
      if (s < NST - 1) {
        int cn = s + 1 + st0; if (cn >= NST) cn -= NST;
        int kn = cn * 128;
        loadA(aS0, kn); loadA(aS1, kn + 32); loadA(aS2, kn + 64); loadA(aS3, kn + 96);
      }
      SB();
      __builtin_amdgcn_s_barrier();
      SB();
      if (s + 2 < NST) { issueD(s + 2, s & 1); SB(); }
    }
#undef DJ

#pragma unroll
    for (int t = 0; t < GTD; ++t) {
#pragma unroll
      for (int r = 0; r < 4; ++r) {
        int m = (tb + t) * 16 + kq * 4 + r;
        if (m < ne) {
          OUTS[(size_t)(base + m) * H_ + hcol] = acc[t][r];
        }
      }
    }
  }
}

// ---------------- Weighted combine ----------------
__global__ __launch_bounds__(256) void combine_kernel(
    const float* __restrict__ OUTS, const float* __restrict__ topk_w,
    const int* __restrict__ slot2g, float* __restrict__ out) {
  int m = blockIdx.x;
  float w[K_]; int g[K_];
#pragma unroll
  for (int k = 0; k < K_; ++k) { w[k] = topk_w[m * K_ + k]; g[k] = slot2g[m * K_ + k]; }
  for (int h = threadIdx.x; h < H_; h += 256) {
    float s = 0.f;
#pragma unroll
    for (int k = 0; k < K_; ++k) s = fmaf(w[k], OUTS[(size_t)g[k] * H_ + h], s);
    out[(size_t)m * H_ + h] = s;
  }
}

extern "C" void kernel_launch(void* const* d_in, const int* in_sizes, int n_in,
                              void* d_out, int out_size, void* d_ws, size_t ws_size,
                              hipStream_t stream) {
  const float* x   = (const float*)d_in[0];
  const float* gw  = (const float*)d_in[1];
  const float* w13 = (const float*)d_in[2];
  const float* w2  = (const float*)d_in[3];
  float* out = (float*)d_out;

  const int M = in_sizes[0] / H_;   // 512
  const int MK = M * K_;            // 4096

  char* ws = (char*)d_ws;
  size_t o = 0;
  auto alloc = [&](size_t bytes) { size_t r = o; o = (o + bytes + 255) & ~(size_t)255; return r; };
  int*   topk_id  = (int*)(ws + alloc((size_t)MK * 4));
  float* topk_w   = (float*)(ws + alloc((size_t)MK * 4));
  int*   cnt      = (int*)(ws + alloc(E_ * 4));
  int*   off      = (int*)(ws + alloc((E_ + 1) * 4));
  int*   perEx    = (int*)(ws + alloc((size_t)E_ * M * 4));
  int*   entry_mk = (int*)(ws + alloc((size_t)MK * 4));
  int*   slot2g   = (int*)(ws + alloc((size_t)MK * 4));
  __hip_bfloat16* xb  = (__hip_bfloat16*)(ws + alloc((size_t)M * H_ * 2));
  __hip_bfloat16* ACT = (__hip_bfloat16*)(ws + alloc((size_t)MK * I_ * 2));
  float* OUTS     = (float*)(ws + alloc((size_t)MK * H_ * 4));
  float* psink    = (float*)(ws + alloc(256));
  (void)ws_size; (void)n_in; (void)out_size;

  // ---- diagnostic probes: ~4GB reads each, self-identifying in rocprof ----
  {
    long n4 = (long)E_ * (2 * I_) * H_ / 4;        // w13 as float4 count
    probe_a<<<2048, 256, 0, stream>>>((const float4*)w13, psink, n4, 5);
    long nf = (long)E_ * H_ * I_;                  // w2 float count
    probe_c<<<768, 256, 0, stream>>>(w2, psink, nf, 10);
  }

  router_kernel<<<M, 256, 0, stream>>>(x, gw, topk_id, topk_w, xb, cnt);
  scatter_kernel<<<(MK + 255) / 256, 256, 0, stream>>>(topk_id, cnt, perEx, MK, M);
  scan_kernel<<<1, 64, 0, stream>>>(cnt, off);
  compact_kernel<<<E_, 256, 0, stream>>>(cnt, off, perEx, entry_mk, slot2g, M);
  gateup_mfma<<<dim3(I_ / 64, E_), 256, 0, stream>>>(xb, w13, cnt, off, entry_mk, ACT);
  down_mfma<<<dim3(H_ / 64, E_), 256, 0, stream>>>(ACT, w2, cnt, off, OUTS);
  combine_kernel<<<M, 256, 0, stream>>>(OUTS, topk_w, slot2g, out);
}

// Round 10
// 428.253 us; speedup vs baseline: 3.8927x; 3.8927x over previous
//
#include <hip/hip_runtime.h>
#include <hip/hip_bf16.h>

#define H_ 2048
#define E_ 64
#define I_ 768
#define K_ 8
#define GT 6          // gateup token tiles per pass (96 tokens)
#define GTD 5         // down token tiles per pass (80 tokens)

typedef __attribute__((ext_vector_type(8))) __bf16 bf16x8;
typedef __attribute__((ext_vector_type(4))) float f32x4;

__device__ inline unsigned short f2bfbits(float f) {
  unsigned u = __float_as_uint(f);
  u = (u + 0x7fffu + ((u >> 16) & 1u)) >> 16;   // RNE
  return (unsigned short)u;
}
__device__ inline f32x4 mfma16(bf16x8 a, bf16x8 b, f32x4 c) {
  return __builtin_amdgcn_mfma_f32_16x16x32_bf16(a, b, c, 0, 0, 0);
}
__device__ inline bf16x8 packv(f32x4 a, f32x4 b) {
  union { unsigned u[4]; bf16x8 v; } r;
  asm("v_cvt_pk_bf16_f32 %0, %1, %2" : "=v"(r.u[0]) : "v"(a[0]), "v"(a[1]));
  asm("v_cvt_pk_bf16_f32 %0, %1, %2" : "=v"(r.u[1]) : "v"(a[2]), "v"(a[3]));
  asm("v_cvt_pk_bf16_f32 %0, %1, %2" : "=v"(r.u[2]) : "v"(b[0]), "v"(b[1]));
  asm("v_cvt_pk_bf16_f32 %0, %1, %2" : "=v"(r.u[3]) : "v"(b[2]), "v"(b[3]));
  return r.v;
}
__device__ inline void dma16(const float* g, float* l) {
  __builtin_amdgcn_global_load_lds(
      (const __attribute__((address_space(1))) float*)g,
      (__attribute__((address_space(3))) float*)l, 16, 0, 0);
}
template <int OFS>
__device__ inline f32x4 dsr(unsigned addr) {
  f32x4 d;
  asm volatile("ds_read_b128 %0, %1 offset:%2" : "=v"(d) : "v"(addr), "n"(OFS));
  return d;
}
#define SB() __builtin_amdgcn_sched_barrier(0)
#define LGKM0() do { asm volatile("s_waitcnt lgkmcnt(0)" ::: "memory"); SB(); } while (0)

// ---------------- Router (fp32-exact) + fused x->bf16 cast + cnt zero --------
__global__ __launch_bounds__(256) void router_kernel(
    const float* __restrict__ x, const float* __restrict__ gw,
    int* __restrict__ topk_id, float* __restrict__ topk_w,
    __hip_bfloat16* __restrict__ xb, int* __restrict__ cnt) {
  __shared__ float xs[H_];
  __shared__ float probs[E_];
  int m = blockIdx.x;
  if (m == 0 && threadIdx.x < E_) cnt[threadIdx.x] = 0;
  const float* xr = x + (size_t)m * H_;
  for (int i = threadIdx.x; i < H_; i += 256) xs[i] = xr[i];
  __syncthreads();
  unsigned short* xbr = reinterpret_cast<unsigned short*>(xb) + (size_t)m * H_;
  for (int i = threadIdx.x; i < H_; i += 256) xbr[i] = f2bfbits(xs[i]);
  int e = threadIdx.x >> 2, part = threadIdx.x & 3;
  const float* gr = gw + (size_t)e * H_ + part * (H_ / 4);
  const float* xx = xs + part * (H_ / 4);
  float s = 0.f;
#pragma unroll 8
  for (int i = 0; i < H_ / 4; ++i) s = fmaf(xx[i], gr[i], s);
  s += __shfl_xor(s, 1);
  s += __shfl_xor(s, 2);
  if (part == 0) probs[e] = s;
  __syncthreads();
  if (threadIdx.x == 0) {
    float mx = -1e30f;
    for (int i = 0; i < E_; ++i) mx = fmaxf(mx, probs[i]);
    float sum = 0.f;
    for (int i = 0; i < E_; ++i) { float p = expf(probs[i] - mx); probs[i] = p; sum += p; }
    float inv = 1.f / sum;
    for (int i = 0; i < E_; ++i) probs[i] *= inv;
    float bw[K_]; int bi[K_]; float wsum = 0.f;
#pragma unroll
    for (int k = 0; k < K_; ++k) {
      float best = -1.f; int b = 0;
      for (int i = 0; i < E_; ++i) if (probs[i] > best) { best = probs[i]; b = i; }
      bw[k] = best; bi[k] = b; wsum += best; probs[b] = -2.f;
    }
    float winv = 1.f / wsum;
#pragma unroll
    for (int k = 0; k < K_; ++k) {
      topk_id[m * K_ + k] = bi[k];
      topk_w[m * K_ + k] = bw[k] * winv;
    }
  }
}

// ---------------- Expert list build ----------------
__global__ void scatter_kernel(const int* __restrict__ topk_id, int* cnt,
                               int* perEx, int MK, int M) {
  int idx = blockIdx.x * 256 + threadIdx.x;
  if (idx >= MK) return;
  int e = topk_id[idx];
  int pos = atomicAdd(cnt + e, 1);
  perEx[e * M + pos] = idx;  // idx == m*K_+k
}

__global__ void scan_kernel(const int* cnt, int* off) {
  if (threadIdx.x == 0) {
    int a = 0;
    for (int e = 0; e < E_; ++e) { off[e] = a; a += cnt[e]; }
    off[E_] = a;
  }
}

__global__ void compact_kernel(const int* __restrict__ cnt, const int* __restrict__ off,
                               const int* __restrict__ perEx,
                               int* __restrict__ entry_mk, int* __restrict__ slot2g, int M) {
  int e = blockIdx.x; int n = cnt[e]; int b = off[e];
  for (int p = threadIdx.x; p < n; p += 256) {
    int mk = perEx[e * M + p];
    entry_mk[b + p] = mk;
    slot2g[mk] = b + p;
  }
}

// ---------------- Gate/Up MFMA GEMM + SiLU -> ACT (bf16) ----------------
// Block-coop 64KB weight stages (128 rows x 512B), 2x dbuf, counted vmcnt.
__global__ __launch_bounds__(256, 1) void gateup_mfma(
    const __hip_bfloat16* __restrict__ xb, const float* __restrict__ w13,
    const int* __restrict__ cnt, const int* __restrict__ off,
    const int* __restrict__ entry_mk, __hip_bfloat16* __restrict__ ACT) {
  __shared__ __align__(16) float lds[2][16384];   // 2 x 64KB
  const int NST = 16;                              // H/128
  int e = blockIdx.y;
  int ne = cnt[e];
  if (ne == 0) return;
  int base = off[e];
  int wv = threadIdx.x >> 6, lane = threadIdx.x & 63;
  int i0 = blockIdx.x * 64;
  int col = lane & 15, kq = lane >> 4;
  int half = lane >> 5, p = lane & 31;
  const float* w13e = w13 + (size_t)e * (2 * I_) * H_;
  int st0 = (blockIdx.x * 7 + blockIdx.y * 3) & (NST - 1);

  int rowC = (wv < 2) ? (i0 + 32 * wv + half) : (I_ + i0 + 32 * wv - 64 + half);
  const float* wbase = w13e + (size_t)rowC * H_;
  int xo[4];
#pragma unroll
  for (int j = 0; j < 4; ++j) xo[j] = (p ^ ((j << 1) | half)) * 4;

  auto issueD = [&](int s, int b) {
    int cs = s + st0; if (cs >= NST) cs -= NST;
    const float* bs = wbase + cs * 128;
#pragma unroll
    for (int q = 0; q < 16; ++q)
      dma16(bs + (size_t)(2 * q) * H_ + xo[q & 3], &lds[b][(16 * wv + q) * 256]);
  };

  unsigned laneOfs = (unsigned)((8 * wv + (col >> 1)) * 1024 + (col & 1) * 512 +
                                (((kq * 2) ^ (col & 7)) * 16));
  unsigned ldsBase = (unsigned)(size_t)(&lds[0][0]);
  int icol = i0 + 16 * wv + col;

  int ntile = (ne + 15) >> 4;
  for (int tb = 0; tb < ntile; tb += GT) {
    const __hip_bfloat16* arow0[GT];
#pragma unroll
    for (int t = 0; t < GT; ++t) {
      int pt = (tb + t) * 16 + col;
      int pc = pt < ne ? pt : ne - 1;
      int tok = entry_mk[base + pc] >> 3;
      arow0[t] = xb + (size_t)tok * H_ + kq * 8;
    }
    f32x4 accg[GT], accu[GT];
#pragma unroll
    for (int t = 0; t < GT; ++t) {
      accg[t] = (f32x4){0.f, 0.f, 0.f, 0.f};
      accu[t] = (f32x4){0.f, 0.f, 0.f, 0.f};
    }
    bf16x8 aS0[GT], aS1[GT], aS2[GT], aS3[GT];
    auto loadA = [&](bf16x8 (&dst)[GT], int kf) {
#pragma unroll
      for (int t = 0; t < GT; ++t)
        dst[t] = *reinterpret_cast<const bf16x8*>(arow0[t] + kf);
    };
    issueD(0, 0); SB();
    { int k0 = st0 * 128;
      loadA(aS0, k0); loadA(aS1, k0 + 32); loadA(aS2, k0 + 64); loadA(aS3, k0 + 96); }
    SB();
    issueD(1, 1); SB();

#define GJ(JOFS, AC)                                                     \
    {                                                                    \
      f32x4 g0 = dsr<(JOFS)>(a0), g1 = dsr<(JOFS)>(a1);                  \
      f32x4 u0 = dsr<(JOFS) + 32768>(a0), u1 = dsr<(JOFS) + 32768>(a1);  \
      LGKM0();                                                           \
      bf16x8 bg = packv(g0, g1), bu = packv(u0, u1);                     \
      _Pragma("unroll")                                                  \
      for (int t = 0; t < GT; ++t) {                                     \
        accg[t] = mfma16(AC[t], bg, accg[t]);                            \
        accu[t] = mfma16(AC[t], bu, accu[t]);                            \
      }                                                                  \
    }

    for (int s = 0; s < NST; ++s) {
      if (s < NST - 1) { asm volatile("s_waitcnt vmcnt(34)" ::: "memory"); }
      else             { asm volatile("s_waitcnt vmcnt(18)" ::: "memory"); }
      SB();
      __builtin_amdgcn_s_barrier();
      SB();
      unsigned a0 = ldsBase + (unsigned)((s & 1) * 65536) + laneOfs;
      unsigned a1 = a0 ^ 16u;
      GJ(0, aS0)
      GJ(128, aS1)
      GJ(256, aS2)
      GJ(384, aS3)
      if (s < NST - 1) {
        int cn = s + 1 + st0; if (cn >= NST) cn -= NST;
        int kn = cn * 128;
        loadA(aS0, kn); loadA(aS1, kn + 32); loadA(aS2, kn + 64); loadA(aS3, kn + 96);
      }
      SB();
      __builtin_amdgcn_s_barrier();
      SB();
      if (s + 2 < NST) { issueD(s + 2, s & 1); SB(); }
    }
#undef GJ

#pragma unroll
    for (int t = 0; t < GT; ++t) {
#pragma unroll
      for (int r = 0; r < 4; ++r) {
        int m = (tb + t) * 16 + kq * 4 + r;
        if (m < ne) {
          float gv = accg[t][r], uv = accu[t][r];
          float act = gv / (1.f + __expf(-gv)) * uv;
          reinterpret_cast<unsigned short*>(ACT)[(size_t)(base + m) * I_ + icol] =
              f2bfbits(act);
        }
      }
    }
  }
}

// ---------------- Down MFMA GEMM -> OUTS (fp32) ----------------
__global__ __launch_bounds__(256, 2) void down_mfma(
    const __hip_bfloat16* __restrict__ ACT, const float* __restrict__ w2,
    const int* __restrict__ cnt, const int* __restrict__ off,
    float* __restrict__ OUTS) {
  __shared__ __align__(16) float lds[2][8192];    // 2 x 32KB
  const int NST = 6;                               // I/128
  int e = blockIdx.y;
  int ne = cnt[e];
  if (ne == 0) return;
  int base = off[e];
  int wv = threadIdx.x >> 6, lane = threadIdx.x & 63;
  int h0 = blockIdx.x * 64;
  int col = lane & 15, kq = lane >> 4;
  int half = lane >> 5, p = lane & 31;
  const float* w2e = w2 + (size_t)e * H_ * I_;
  int st0 = (int)((unsigned)(blockIdx.x + blockIdx.y * 5) % (unsigned)NST);

  const float* wbase = w2e + (size_t)(h0 + 16 * wv + half) * I_;
  int xo[4];
#pragma unroll
  for (int j = 0; j < 4; ++j) xo[j] = (p ^ ((j << 1) | half)) * 4;

  auto issueD = [&](int s, int b) {
    int cs = s + st0; if (cs >= NST) cs -= NST;
    const float* bs = wbase + cs * 128;
#pragma unroll
    for (int q = 0; q < 8; ++q)
      dma16(bs + (size_t)(2 * q) * I_ + xo[q & 3], &lds[b][(8 * wv + q) * 256]);
  };

  unsigned laneOfs = (unsigned)((8 * wv + (col >> 1)) * 1024 + (col & 1) * 512 +
                                (((kq * 2) ^ (col & 7)) * 16));
  unsigned ldsBase = (unsigned)(size_t)(&lds[0][0]);
  int hcol = h0 + 16 * wv + col;

  int ntile = (ne + 15) >> 4;
  for (int tb = 0; tb < ntile; tb += GTD) {
    const __hip_bfloat16* arow0[GTD];
#pragma unroll
    for (int t = 0; t < GTD; ++t) {
      int pt = (tb + t) * 16 + col;
      int pc = pt < ne ? pt : ne - 1;
      arow0[t] = ACT + (size_t)(base + pc) * I_ + kq * 8;
    }
    f32x4 acc[GTD];
#pragma unroll
    for (int t = 0; t < GTD; ++t) acc[t] = (f32x4){0.f, 0.f, 0.f, 0.f};
    bf16x8 aS0[GTD], aS1[GTD], aS2[GTD], aS3[GTD];
    auto loadA = [&](bf16x8 (&dst)[GTD], int kf) {
#pragma unroll
      for (int t = 0; t < GTD; ++t)
        dst[t] = *reinterpret_cast<const bf16x8*>(arow0[t] + kf);
    };
    issueD(0, 0); SB();
    { int k0 = st0 * 128;
      loadA(aS0, k0); loadA(aS1, k0 + 32); loadA(aS2, k0 + 64); loadA(aS3, k0 + 96); }
    SB();
    issueD(1, 1); SB();

#define DJ(JOFS, AC)                                                     \
    {                                                                    \
      f32x4 w0 = dsr<(JOFS)>(a0), w1 = dsr<(JOFS)>(a1);                  \
      LGKM0();                                                           \
      bf16x8 bw = packv(w0, w1);                                         \
      _Pragma("unroll")                                                  \
      for (int t = 0; t < GTD; ++t) acc[t] = mfma16(AC[t], bw, acc[t]);  \
    }

    for (int s = 0; s < NST; ++s) {
      if (s < NST - 1) { asm volatile("s_waitcnt vmcnt(23)" ::: "memory"); }
      else             { asm volatile("s_waitcnt vmcnt(15)" ::: "memory"); }
      SB();
      __builtin_amdgcn_s_barrier();
      SB();
      unsigned a0 = ldsBase + (unsigned)((s & 1) * 32768) + laneOfs;
      unsigned a1 = a0 ^ 16u;
      DJ(0, aS0)
      DJ(128, aS1)
      DJ(256, aS2)
      DJ(384, aS3)
      if (s < NST - 1) {
        int cn = s + 1 + st0; if (cn >= NST) cn -= NST;
        int kn = cn * 128;
        loadA(aS0, kn); loadA(aS1, kn + 32); loadA(aS2, kn + 64); loadA(aS3, kn + 96);
      }
      SB();
      __builtin_amdgcn_s_barrier();
      SB();
      if (s + 2 < NST) { issueD(s + 2, s & 1); SB(); }
    }
#undef DJ

#pragma unroll
    for (int t = 0; t < GTD; ++t) {
#pragma unroll
      for (int r = 0; r < 4; ++r) {
        int m = (tb + t) * 16 + kq * 4 + r;
        if (m < ne) {
          OUTS[(size_t)(base + m) * H_ + hcol] = acc[t][r];
        }
      }
    }
  }
}

// ---------------- Weighted combine ----------------
__global__ __launch_bounds__(256) void combine_kernel(
    const float* __restrict__ OUTS, const float* __restrict__ topk_w,
    const int* __restrict__ slot2g, float* __restrict__ out) {
  int m = blockIdx.x;
  float w[K_]; int g[K_];
#pragma unroll
  for (int k = 0; k < K_; ++k) { w[k] = topk_w[m * K_ + k]; g[k] = slot2g[m * K_ + k]; }
  for (int h = threadIdx.x; h < H_; h += 256) {
    float s = 0.f;
#pragma unroll
    for (int k = 0; k < K_; ++k) s = fmaf(w[k], OUTS[(size_t)g[k] * H_ + h], s);
    out[(size_t)m * H_ + h] = s;
  }
}

extern "C" void kernel_launch(void* const* d_in, const int* in_sizes, int n_in,
                              void* d_out, int out_size, void* d_ws, size_t ws_size,
                              hipStream_t stream) {
  const float* x   = (const float*)d_in[0];
  const float* gw  = (const float*)d_in[1];
  const float* w13 = (const float*)d_in[2];
  const float* w2  = (const float*)d_in[3];
  float* out = (float*)d_out;

  const int M = in_sizes[0] / H_;   // 512
  const int MK = M * K_;            // 4096

  char* ws = (char*)d_ws;
  size_t o = 0;
  auto alloc = [&](size_t bytes) { size_t r = o; o = (o + bytes + 255) & ~(size_t)255; return r; };
  int*   topk_id  = (int*)(ws + alloc((size_t)MK * 4));
  float* topk_w   = (float*)(ws + alloc((size_t)MK * 4));
  int*   cnt      = (int*)(ws + alloc(E_ * 4));
  int*   off      = (int*)(ws + alloc((E_ + 1) * 4));
  int*   perEx    = (int*)(ws + alloc((size_t)E_ * M * 4));
  int*   entry_mk = (int*)(ws + alloc((size_t)MK * 4));
  int*   slot2g   = (int*)(ws + alloc((size_t)MK * 4));
  __hip_bfloat16* xb  = (__hip_bfloat16*)(ws + alloc((size_t)M * H_ * 2));
  __hip_bfloat16* ACT = (__hip_bfloat16*)(ws + alloc((size_t)MK * I_ * 2));
  float* OUTS     = (float*)(ws + alloc((size_t)MK * H_ * 4));
  (void)ws_size; (void)n_in; (void)out_size;

  router_kernel<<<M, 256, 0, stream>>>(x, gw, topk_id, topk_w, xb, cnt);
  scatter_kernel<<<(MK + 255) / 256, 256, 0, stream>>>(topk_id, cnt, perEx, MK, M);
  scan_kernel<<<1, 64, 0, stream>>>(cnt, off);
  compact_kernel<<<E_, 256, 0, stream>>>(cnt, off, perEx, entry_mk, slot2g, M);
  gateup_mfma<<<dim3(I_ / 64, E_), 256, 0, stream>>>(xb, w13, cnt, off, entry_mk, ACT);
  down_mfma<<<dim3(H_ / 64, E_), 256, 0, stream>>>(ACT, w2, cnt, off, OUTS);
  combine_kernel<<<M, 256, 0, stream>>>(OUTS, topk_w, slot2g, out);
}